// Round 2
// baseline (508.407 us; speedup 1.0000x reference)
//
#include <hip/hip_runtime.h>

#define DEVI __device__ __forceinline__

typedef __attribute__((ext_vector_type(8))) short bf16x8;
typedef __attribute__((ext_vector_type(4))) float f32x4;

// ---------- helpers ----------
DEVI unsigned short f2bf(float f) {
  unsigned int u = __float_as_uint(f);
  unsigned int r = (u + 0x7FFFu + ((u >> 16) & 1u)) >> 16;
  return (unsigned short)r;
}

DEVI void gl16(const void* g, void* l) {
  __builtin_amdgcn_global_load_lds((const __attribute__((address_space(1))) void*)g,
                                   (__attribute__((address_space(3))) void*)l, 16, 0, 0);
}

DEVI float rmax16(float v) {
  v = fmaxf(v, __shfl_xor(v, 1));
  v = fmaxf(v, __shfl_xor(v, 2));
  v = fmaxf(v, __shfl_xor(v, 4));
  v = fmaxf(v, __shfl_xor(v, 8));
  return v;
}
DEVI float rsum16(float v) {
  v += __shfl_xor(v, 1);
  v += __shfl_xor(v, 2);
  v += __shfl_xor(v, 4);
  v += __shfl_xor(v, 8);
  return v;
}

// ---------- fp32 -> bf16 convert ----------
__global__ void cvt_f32_bf16(const float* __restrict__ in, unsigned short* __restrict__ out, int n) {
  int i = (blockIdx.x * 256 + threadIdx.x) * 4;
  if (i >= n) return;
  float4 v = *reinterpret_cast<const float4*>(in + i);
  ushort4 o;
  o.x = f2bf(v.x); o.y = f2bf(v.y); o.z = f2bf(v.z); o.w = f2bf(v.w);
  *reinterpret_cast<ushort4*>(out + i) = o;
}

// ---------- GEMM: C[M,N] = A[M,K] * B[N,K]^T + bias ----------
// m97 structure: 128x128 tile, BK=64, 4 waves (2x2), 16x16x32 bf16 MFMA.
template <int OUT_BF16>
__global__ __launch_bounds__(256) void gemm_bt(
    const unsigned short* __restrict__ A, const unsigned short* __restrict__ B,
    const float* __restrict__ bias, void* __restrict__ Cv, int M, int N, int K) {
  __shared__ __align__(16) unsigned short lA[128 * 64];
  __shared__ __align__(16) unsigned short lB[128 * 64];
  const int t = threadIdx.x;
  const int wid = t >> 6, lane = t & 63, lr = lane & 15, lg = lane >> 4;
  const int wm = wid >> 1, wn = wid & 1;
  const int m0 = blockIdx.y * 128, n0 = blockIdx.x * 128;

  f32x4 acc[4][4] = {};

  for (int kb = 0; kb < K; kb += 64) {
    __syncthreads();
#pragma unroll
    for (int i = 0; i < 4; i++) {
      const int u = i * 256 + t;       // 16B unit index, 0..1023
      const int row = u >> 3;          // tile row
      const int ke = (u & 7) * 8;      // k element start
      // wave-uniform LDS base (+ lane*16 done by HW)
      unsigned short* la = lA + (size_t)(i * 256 + wid * 64) * 8;
      unsigned short* lb = lB + (size_t)(i * 256 + wid * 64) * 8;
      gl16(A + (size_t)(m0 + row) * K + kb + ke, la);
      gl16(B + (size_t)(n0 + row) * K + kb + ke, lb);
    }
    __syncthreads();
#pragma unroll
    for (int kk = 0; kk < 2; kk++) {
      bf16x8 af[4], bfr[4];
#pragma unroll
      for (int m = 0; m < 4; m++)
        af[m] = *reinterpret_cast<const bf16x8*>(&lA[(wm * 64 + m * 16 + lr) * 64 + kk * 32 + lg * 8]);
#pragma unroll
      for (int n = 0; n < 4; n++)
        bfr[n] = *reinterpret_cast<const bf16x8*>(&lB[(wn * 64 + n * 16 + lr) * 64 + kk * 32 + lg * 8]);
#pragma unroll
      for (int m = 0; m < 4; m++)
#pragma unroll
        for (int n = 0; n < 4; n++)
          acc[m][n] = __builtin_amdgcn_mfma_f32_16x16x32_bf16(af[m], bfr[n], acc[m][n], 0, 0, 0);
    }
  }

#pragma unroll
  for (int m = 0; m < 4; m++)
#pragma unroll
    for (int n = 0; n < 4; n++)
#pragma unroll
      for (int r = 0; r < 4; r++) {
        const int row = m0 + wm * 64 + m * 16 + lg * 4 + r;
        const int col = n0 + wn * 64 + n * 16 + lr;
        float v = acc[m][n][r] + bias[col];
        if (OUT_BF16)
          ((unsigned short*)Cv)[(size_t)row * N + col] = f2bf(v);
        else
          ((float*)Cv)[(size_t)row * N + col] = v;
      }
}

// ---------- causal flash attention ----------
// grid: (S/64, H); block 256 = 4 waves; wave handles 16 q rows. KV tile = 64.
#define SEQ 4096
#define NH 16
#define HD 64
__global__ __launch_bounds__(256) void attn_fwd(
    const unsigned short* __restrict__ Qb, const unsigned short* __restrict__ Kb,
    const unsigned short* __restrict__ Vb, unsigned short* __restrict__ Ob) {
  const int h = blockIdx.y;
  const int qt = blockIdx.x;
  const int t = threadIdx.x;
  const int wid = t >> 6, lane = t & 63, lr = lane & 15, lg = lane >> 4;
  const int q0 = qt * 64;

  __shared__ __align__(16) unsigned short Kt[64][72];
  __shared__ __align__(16) unsigned short Vt[64][72];  // transposed: [dv][kv]
  __shared__ __align__(16) unsigned short Pl[4][16][72];

  // Q fragments (A operand): row = lane&15, k = (lane>>4)*8 .. +8 (+32 for chunk 1)
  bf16x8 qf[2];
  const int qrow = q0 + wid * 16 + lr;
#pragma unroll
  for (int c = 0; c < 2; c++)
    qf[c] = *reinterpret_cast<const bf16x8*>(&Qb[(size_t)qrow * (NH * HD) + h * HD + c * 32 + lg * 8]);

  f32x4 accO[4] = {};
  float mrow[4] = {-INFINITY, -INFINITY, -INFINITY, -INFINITY};
  float lrow[4] = {0.f, 0.f, 0.f, 0.f};

  const int ntile = qt + 1;
  for (int tk = 0; tk < ntile; tk++) {
    const int kv0 = tk * 64;
    __syncthreads();
    // stage K row-major and V transposed
    {
      const int r = t >> 2, cs = (t & 3) * 16;
      const unsigned short* ksrc = Kb + (size_t)(kv0 + r) * (NH * HD) + h * HD + cs;
      *(uint4*)&Kt[r][cs] = *(const uint4*)ksrc;
      *(uint4*)&Kt[r][cs + 8] = *(const uint4*)(ksrc + 8);
      const unsigned short* vsrc = Vb + (size_t)(kv0 + r) * (NH * HD) + h * HD + cs;
      unsigned short tmp[16];
      *(uint4*)&tmp[0] = *(const uint4*)vsrc;
      *(uint4*)&tmp[8] = *(const uint4*)(vsrc + 8);
#pragma unroll
      for (int j = 0; j < 16; j++) Vt[cs + j][r] = tmp[j];
    }
    __syncthreads();

    // QK^T: S[16q x 64k], 4 k-subtiles
    f32x4 s[4];
#pragma unroll
    for (int ks = 0; ks < 4; ks++) {
      bf16x8 kf0 = *reinterpret_cast<const bf16x8*>(&Kt[ks * 16 + lr][lg * 8]);
      bf16x8 kf1 = *reinterpret_cast<const bf16x8*>(&Kt[ks * 16 + lr][32 + lg * 8]);
      f32x4 a = {};
      a = __builtin_amdgcn_mfma_f32_16x16x32_bf16(qf[0], kf0, a, 0, 0, 0);
      a = __builtin_amdgcn_mfma_f32_16x16x32_bf16(qf[1], kf1, a, 0, 0, 0);
      s[ks] = a;
    }
    // scale + causal mask (only diagonal tile needs masking)
    if (tk == qt) {
#pragma unroll
      for (int ks = 0; ks < 4; ks++) {
        const int kg = kv0 + ks * 16 + lr;
#pragma unroll
        for (int r = 0; r < 4; r++) {
          const int qg = q0 + wid * 16 + lg * 4 + r;
          s[ks][r] = (kg <= qg) ? s[ks][r] * 0.125f : -INFINITY;
        }
      }
    } else {
#pragma unroll
      for (int ks = 0; ks < 4; ks++)
#pragma unroll
        for (int r = 0; r < 4; r++) s[ks][r] *= 0.125f;
    }
    // online softmax (row reductions within 16-lane groups)
    float a4[4];
#pragma unroll
    for (int r = 0; r < 4; r++) {
      float tm = fmaxf(fmaxf(s[0][r], s[1][r]), fmaxf(s[2][r], s[3][r]));
      tm = rmax16(tm);
      const float mn = fmaxf(mrow[r], tm);
      const float al = __expf(mrow[r] - mn);
      mrow[r] = mn;
      float rs = 0.f;
#pragma unroll
      for (int ks = 0; ks < 4; ks++) {
        float pv = __expf(s[ks][r] - mn);
        s[ks][r] = pv;
        rs += pv;
      }
      rs = rsum16(rs);
      lrow[r] = lrow[r] * al + rs;
      a4[r] = al;
    }
#pragma unroll
    for (int dv = 0; dv < 4; dv++)
#pragma unroll
      for (int r = 0; r < 4; r++) accO[dv][r] *= a4[r];
    // P -> LDS (per-wave region), C/D layout -> A layout
#pragma unroll
    for (int ks = 0; ks < 4; ks++)
#pragma unroll
      for (int r = 0; r < 4; r++) Pl[wid][lg * 4 + r][ks * 16 + lr] = f2bf(s[ks][r]);
    __syncthreads();
    // PV: O += P[16x64] * V[64x64]
    bf16x8 pa0 = *reinterpret_cast<const bf16x8*>(&Pl[wid][lr][lg * 8]);
    bf16x8 pa1 = *reinterpret_cast<const bf16x8*>(&Pl[wid][lr][32 + lg * 8]);
#pragma unroll
    for (int dv = 0; dv < 4; dv++) {
      bf16x8 vb0 = *reinterpret_cast<const bf16x8*>(&Vt[dv * 16 + lr][lg * 8]);
      bf16x8 vb1 = *reinterpret_cast<const bf16x8*>(&Vt[dv * 16 + lr][32 + lg * 8]);
      accO[dv] = __builtin_amdgcn_mfma_f32_16x16x32_bf16(pa0, vb0, accO[dv], 0, 0, 0);
      accO[dv] = __builtin_amdgcn_mfma_f32_16x16x32_bf16(pa1, vb1, accO[dv], 0, 0, 0);
    }
  }

  // normalize + store
#pragma unroll
  for (int dv = 0; dv < 4; dv++)
#pragma unroll
    for (int r = 0; r < 4; r++) {
      const int row = q0 + wid * 16 + lg * 4 + r;
      const int col = h * HD + dv * 16 + lr;
      Ob[(size_t)row * (NH * HD) + col] = f2bf(accO[dv][r] / lrow[r]);
    }
}

// ---------- launch ----------
extern "C" void kernel_launch(void* const* d_in, const int* in_sizes, int n_in,
                              void* d_out, int out_size, void* d_ws, size_t ws_size,
                              hipStream_t stream) {
  const float* queries = (const float*)d_in[0];
  const float* keys    = (const float*)d_in[1];
  const float* values  = (const float*)d_in[2];
  const float* Wq = (const float*)d_in[3];
  const float* bq = (const float*)d_in[4];
  const float* Wk = (const float*)d_in[5];
  const float* bk = (const float*)d_in[6];
  const float* Wv = (const float*)d_in[7];
  const float* bv = (const float*)d_in[8];
  const float* Wo = (const float*)d_in[9];
  const float* bo = (const float*)d_in[10];
  float* out = (float*)d_out;

  const int S = 4096, D = 1024;
  const int SD = S * D;      // 4M
  const int DD = D * D;      // 1M

  unsigned short* p = (unsigned short*)d_ws;
  unsigned short* xq = p; p += SD;
  unsigned short* xk = p; p += SD;
  unsigned short* xv = p; p += SD;
  unsigned short* wq = p; p += DD;
  unsigned short* wk = p; p += DD;
  unsigned short* wv = p; p += DD;
  unsigned short* wo = p; p += DD;
  unsigned short* Qb = p; p += SD;
  unsigned short* Kb = p; p += SD;
  unsigned short* Vb = p; p += SD;
  unsigned short* Ob = xq;   // alias: xq is dead after the Q projection

  cvt_f32_bf16<<<SD / 1024, 256, 0, stream>>>(queries, xq, SD);
  cvt_f32_bf16<<<SD / 1024, 256, 0, stream>>>(keys, xk, SD);
  cvt_f32_bf16<<<SD / 1024, 256, 0, stream>>>(values, xv, SD);
  cvt_f32_bf16<<<DD / 1024, 256, 0, stream>>>(Wq, wq, DD);
  cvt_f32_bf16<<<DD / 1024, 256, 0, stream>>>(Wk, wk, DD);
  cvt_f32_bf16<<<DD / 1024, 256, 0, stream>>>(Wv, wv, DD);
  cvt_f32_bf16<<<DD / 1024, 256, 0, stream>>>(Wo, wo, DD);

  dim3 gg(D / 128, S / 128), gb(256);
  gemm_bt<1><<<gg, gb, 0, stream>>>(xq, wq, bq, Qb, S, D, D);
  gemm_bt<1><<<gg, gb, 0, stream>>>(xk, wk, bk, Kb, S, D, D);
  gemm_bt<1><<<gg, gb, 0, stream>>>(xv, wv, bv, Vb, S, D, D);

  attn_fwd<<<dim3(S / 64, NH), 256, 0, stream>>>(Qb, Kb, Vb, Ob);

  gemm_bt<0><<<gg, gb, 0, stream>>>(Ob, wo, bo, out, S, D, D);
}

// Round 3
// 331.861 us; speedup vs baseline: 1.5320x; 1.5320x over previous
//
#include <hip/hip_runtime.h>

#define DEVI __device__ __forceinline__

typedef __attribute__((ext_vector_type(8))) short bf16x8;
typedef __attribute__((ext_vector_type(4))) float f32x4;

#define SQL 4096
#define DM 1024
#define NH 16
#define HD 64
#define S64 (SQL * HD)  // per-head plane elems

// ---------- helpers ----------
DEVI unsigned short f2bf(float f) {
  unsigned int u = __float_as_uint(f);
  unsigned int r = (u + 0x7FFFu + ((u >> 16) & 1u)) >> 16;
  return (unsigned short)r;
}

DEVI void gl16(const void* g, void* l) {
  __builtin_amdgcn_global_load_lds((const __attribute__((address_space(1))) void*)g,
                                   (__attribute__((address_space(3))) void*)l, 16, 0, 0);
}

DEVI float rmax16(float v) {
  v = fmaxf(v, __shfl_xor(v, 1));
  v = fmaxf(v, __shfl_xor(v, 2));
  v = fmaxf(v, __shfl_xor(v, 4));
  v = fmaxf(v, __shfl_xor(v, 8));
  return v;
}
DEVI float rsum16(float v) {
  v += __shfl_xor(v, 1);
  v += __shfl_xor(v, 2);
  v += __shfl_xor(v, 4);
  v += __shfl_xor(v, 8);
  return v;
}

DEVI f32x4 mfma16(bf16x8 a, bf16x8 b, f32x4 c) {
  return __builtin_amdgcn_mfma_f32_16x16x32_bf16(a, b, c, 0, 0, 0);
}

// ---------- fused fp32 -> bf16 convert (7 tensors, 1 dispatch) ----------
__global__ void cvt_all(const float* __restrict__ q, const float* __restrict__ k,
                        const float* __restrict__ v, const float* __restrict__ Wq,
                        const float* __restrict__ Wk, const float* __restrict__ Wv,
                        const float* __restrict__ Wo, unsigned short* __restrict__ o) {
  const size_t SD = (size_t)SQL * DM, DD = (size_t)DM * DM;
  size_t i = ((size_t)blockIdx.x * 256 + threadIdx.x) * 4;
  const float* src;
  size_t base;
  if (i < SD) { src = q; base = 0; }
  else if (i < 2 * SD) { src = k; base = SD; }
  else if (i < 3 * SD) { src = v; base = 2 * SD; }
  else if (i < 3 * SD + DD) { src = Wq; base = 3 * SD; }
  else if (i < 3 * SD + 2 * DD) { src = Wk; base = 3 * SD + DD; }
  else if (i < 3 * SD + 3 * DD) { src = Wv; base = 3 * SD + 2 * DD; }
  else { src = Wo; base = 3 * SD + 3 * DD; }
  float4 vv = *reinterpret_cast<const float4*>(src + (i - base));
  ushort4 ov;
  ov.x = f2bf(vv.x); ov.y = f2bf(vv.y); ov.z = f2bf(vv.z); ov.w = f2bf(vv.w);
  *reinterpret_cast<ushort4*>(o + i) = ov;
}

// ---------- batched QKV GEMM: z selects (A,B,bias,dst,outmode) ----------
// C[M=4096, N=1024] = A[M,K=1024] * B[N,K]^T + bias
// z=0,1 -> head-major bf16 [h][s][d]; z=2 -> V^T bf16 [h][d][s]
__global__ __launch_bounds__(256) void gemm_qkv(
    const unsigned short* __restrict__ xq, const unsigned short* __restrict__ xk,
    const unsigned short* __restrict__ xv, const unsigned short* __restrict__ wq,
    const unsigned short* __restrict__ wk, const unsigned short* __restrict__ wv,
    const float* __restrict__ bq, const float* __restrict__ bk, const float* __restrict__ bv,
    unsigned short* __restrict__ Qh, unsigned short* __restrict__ Kh,
    unsigned short* __restrict__ VT) {
  __shared__ __align__(16) unsigned short lA[128 * 64];
  __shared__ __align__(16) unsigned short lB[128 * 64];
  const int z = blockIdx.z;
  const unsigned short* A = (z == 0) ? xq : (z == 1) ? xk : xv;
  const unsigned short* B = (z == 0) ? wq : (z == 1) ? wk : wv;
  const float* bias = (z == 0) ? bq : (z == 1) ? bk : bv;

  const int t = threadIdx.x;
  const int wid = t >> 6, lane = t & 63, lr = lane & 15, lg = lane >> 4;
  const int wm = wid >> 1, wn = wid & 1;
  const int m0 = blockIdx.y * 128, n0 = blockIdx.x * 128;
  const int K = DM, N = DM;

  f32x4 acc[4][4] = {};

  for (int kb = 0; kb < K; kb += 64) {
    __syncthreads();
#pragma unroll
    for (int i = 0; i < 4; i++) {
      const int u = i * 256 + t;
      const int row = u >> 3;
      const int ke = (u & 7) * 8;
      unsigned short* la = lA + (size_t)(i * 256 + wid * 64) * 8;
      unsigned short* lb = lB + (size_t)(i * 256 + wid * 64) * 8;
      gl16(A + (size_t)(m0 + row) * K + kb + ke, la);
      gl16(B + (size_t)(n0 + row) * K + kb + ke, lb);
    }
    __syncthreads();
#pragma unroll
    for (int kk = 0; kk < 2; kk++) {
      bf16x8 af[4], bfr[4];
#pragma unroll
      for (int m = 0; m < 4; m++)
        af[m] = *reinterpret_cast<const bf16x8*>(&lA[(wm * 64 + m * 16 + lr) * 64 + kk * 32 + lg * 8]);
#pragma unroll
      for (int n = 0; n < 4; n++)
        bfr[n] = *reinterpret_cast<const bf16x8*>(&lB[(wn * 64 + n * 16 + lr) * 64 + kk * 32 + lg * 8]);
#pragma unroll
      for (int m = 0; m < 4; m++)
#pragma unroll
        for (int n = 0; n < 4; n++)
          acc[m][n] = mfma16(af[m], bfr[n], acc[m][n]);
    }
  }

  unsigned short* dstQK = (z == 0) ? Qh : Kh;
#pragma unroll
  for (int m = 0; m < 4; m++)
#pragma unroll
    for (int n = 0; n < 4; n++) {
      const int col = n0 + wn * 64 + n * 16 + lr;
      const int h = col >> 6, d = col & 63;
      const int row0 = m0 + wm * 64 + m * 16 + lg * 4;
      const float bsv = bias[col];
      if (z < 2) {
#pragma unroll
        for (int r = 0; r < 4; r++)
          dstQK[(size_t)h * S64 + (size_t)(row0 + r) * HD + d] = f2bf(acc[m][n][r] + bsv);
      } else {
        ushort4 ov;
        ov.x = f2bf(acc[m][n][0] + bsv);
        ov.y = f2bf(acc[m][n][1] + bsv);
        ov.z = f2bf(acc[m][n][2] + bsv);
        ov.w = f2bf(acc[m][n][3] + bsv);
        *reinterpret_cast<ushort4*>(&VT[(size_t)h * S64 + (size_t)d * SQL + row0]) = ov;
      }
    }
}

// ---------- final GEMM: out[M,N] fp32 = A[M,K] * B[N,K]^T + bias ----------
__global__ __launch_bounds__(256) void gemm_out(
    const unsigned short* __restrict__ A, const unsigned short* __restrict__ B,
    const float* __restrict__ bias, float* __restrict__ C) {
  __shared__ __align__(16) unsigned short lA[128 * 64];
  __shared__ __align__(16) unsigned short lB[128 * 64];
  const int t = threadIdx.x;
  const int wid = t >> 6, lane = t & 63, lr = lane & 15, lg = lane >> 4;
  const int wm = wid >> 1, wn = wid & 1;
  const int m0 = blockIdx.y * 128, n0 = blockIdx.x * 128;
  const int K = DM, N = DM;

  f32x4 acc[4][4] = {};

  for (int kb = 0; kb < K; kb += 64) {
    __syncthreads();
#pragma unroll
    for (int i = 0; i < 4; i++) {
      const int u = i * 256 + t;
      const int row = u >> 3;
      const int ke = (u & 7) * 8;
      unsigned short* la = lA + (size_t)(i * 256 + wid * 64) * 8;
      unsigned short* lb = lB + (size_t)(i * 256 + wid * 64) * 8;
      gl16(A + (size_t)(m0 + row) * K + kb + ke, la);
      gl16(B + (size_t)(n0 + row) * K + kb + ke, lb);
    }
    __syncthreads();
#pragma unroll
    for (int kk = 0; kk < 2; kk++) {
      bf16x8 af[4], bfr[4];
#pragma unroll
      for (int m = 0; m < 4; m++)
        af[m] = *reinterpret_cast<const bf16x8*>(&lA[(wm * 64 + m * 16 + lr) * 64 + kk * 32 + lg * 8]);
#pragma unroll
      for (int n = 0; n < 4; n++)
        bfr[n] = *reinterpret_cast<const bf16x8*>(&lB[(wn * 64 + n * 16 + lr) * 64 + kk * 32 + lg * 8]);
#pragma unroll
      for (int m = 0; m < 4; m++)
#pragma unroll
        for (int n = 0; n < 4; n++)
          acc[m][n] = mfma16(af[m], bfr[n], acc[m][n]);
    }
  }

#pragma unroll
  for (int m = 0; m < 4; m++)
#pragma unroll
    for (int n = 0; n < 4; n++)
#pragma unroll
      for (int r = 0; r < 4; r++) {
        const int row = m0 + wm * 64 + m * 16 + lg * 4 + r;
        const int col = n0 + wn * 64 + n * 16 + lr;
        C[(size_t)row * N + col] = acc[m][n][r] + bias[col];
      }
}

// ---------- causal flash attention ----------
// 1-D grid of 1024 blocks; h = bid&15 (fast), qt window-balanced.
// Inputs head-major: Qh/Kh [h][s][64], VT [h][64][s]. Output Ob [s][1024].
// LDS: K,V double-buffered 8KB tiles, XOR-swizzled (byte ^= (row&7)<<4),
// staged via global_load_lds with pre-swizzled global source (rule #21).
__global__ __launch_bounds__(256) void attn_fwd(
    const unsigned short* __restrict__ Qh, const unsigned short* __restrict__ Kh,
    const unsigned short* __restrict__ VT, unsigned short* __restrict__ Ob) {
  const int bid = blockIdx.x;
  const int h = bid & 15;
  const int i6 = bid >> 4;                 // 0..63
  const int jj = i6 & 15, bb = i6 >> 4;    // window-balanced qt map:
  const int qt = (bb & 1) ? (bb * 16 + 15 - jj) : (bb * 16 + jj);
  const int t = threadIdx.x;
  const int wid = t >> 6, lane = t & 63, lr = lane & 15, lg = lane >> 4;
  const int q0 = qt * 64;

  __shared__ __align__(16) unsigned short Kt[2][4096];
  __shared__ __align__(16) unsigned short Vt[2][4096];
  __shared__ __align__(16) unsigned short Pl[4][1024];

  const unsigned short* Kp = Kh + (size_t)h * S64;
  const unsigned short* Vp = VT + (size_t)h * S64;

  bf16x8 qf[2];
  {
    const unsigned short* qp = Qh + (size_t)h * S64 + (size_t)(q0 + wid * 16 + lr) * HD + lg * 8;
    qf[0] = *reinterpret_cast<const bf16x8*>(qp);
    qf[1] = *reinterpret_cast<const bf16x8*>(qp + 32);
  }

  f32x4 accO[4] = {};
  float mrow[4] = {-INFINITY, -INFINITY, -INFINITY, -INFINITY};
  float lrow[4] = {0.f, 0.f, 0.f, 0.f};

  const int xsw = (lr & 7) << 4;  // read-side XOR (row&7 == lr&7 for all our reads)
  unsigned short* pw = &Pl[wid][0];

  const int ntile = qt + 1;

  // prologue: stage tile 0 -> buf 0
#pragma unroll
  for (int ro = 0; ro < 2; ro++) {
    const int u = ro * 256 + t;
    const int row = u >> 3, slot = (u & 7) ^ (row & 7);
    gl16(Kp + (size_t)row * HD + slot * 8, &Kt[0][(ro * 256 + wid * 64) * 8]);
    gl16(Vp + (size_t)row * SQL + slot * 8, &Vt[0][(ro * 256 + wid * 64) * 8]);
  }

  int cur = 0;
  for (int tk = 0; tk < ntile; tk++) {
    const int kv0 = tk * 64;
    __syncthreads();  // drains vmcnt(0): buf[cur] fully landed for all waves

    if (tk + 1 < ntile) {
      const int nkv = kv0 + 64;
      unsigned short* kd = Kt[cur ^ 1];
      unsigned short* vd = Vt[cur ^ 1];
#pragma unroll
      for (int ro = 0; ro < 2; ro++) {
        const int u = ro * 256 + t;
        const int row = u >> 3, slot = (u & 7) ^ (row & 7);
        gl16(Kp + (size_t)(nkv + row) * HD + slot * 8, kd + (ro * 256 + wid * 64) * 8);
        gl16(Vp + (size_t)row * SQL + nkv + slot * 8, vd + (ro * 256 + wid * 64) * 8);
      }
    }

    const char* kt = (const char*)Kt[cur];
    const char* vt = (const char*)Vt[cur];

    // QK^T: S[16q x 64kv]
    f32x4 s[4];
#pragma unroll
    for (int ks = 0; ks < 4; ks++) {
      const char* rb = kt + (ks * 16 + lr) * 128;
      bf16x8 kf0 = *reinterpret_cast<const bf16x8*>(rb + ((lg * 16) ^ xsw));
      bf16x8 kf1 = *reinterpret_cast<const bf16x8*>(rb + ((64 + lg * 16) ^ xsw));
      f32x4 a = {};
      a = mfma16(qf[0], kf0, a);
      a = mfma16(qf[1], kf1, a);
      s[ks] = a;
    }

    // scale + causal mask (diagonal tile only)
    if (tk == qt) {
#pragma unroll
      for (int ks = 0; ks < 4; ks++) {
        const int kg = kv0 + ks * 16 + lr;
#pragma unroll
        for (int r = 0; r < 4; r++) {
          const int qg = q0 + wid * 16 + lg * 4 + r;
          s[ks][r] = (kg <= qg) ? s[ks][r] * 0.125f : -INFINITY;
        }
      }
    } else {
#pragma unroll
      for (int ks = 0; ks < 4; ks++)
#pragma unroll
        for (int r = 0; r < 4; r++) s[ks][r] *= 0.125f;
    }

    // online softmax
    float a4[4];
#pragma unroll
    for (int r = 0; r < 4; r++) {
      float tm = fmaxf(fmaxf(s[0][r], s[1][r]), fmaxf(s[2][r], s[3][r]));
      tm = rmax16(tm);
      const float mn = fmaxf(mrow[r], tm);
      const float al = __expf(mrow[r] - mn);
      mrow[r] = mn;
      float rs = 0.f;
#pragma unroll
      for (int ks = 0; ks < 4; ks++) {
        float pv = __expf(s[ks][r] - mn);
        s[ks][r] = pv;
        rs += pv;
      }
      rs = rsum16(rs);
      lrow[r] = lrow[r] * al + rs;
      a4[r] = al;
    }
#pragma unroll
    for (int dv = 0; dv < 4; dv++)
#pragma unroll
      for (int r = 0; r < 4; r++) accO[dv][r] *= a4[r];

    // P -> per-wave LDS (swizzled; no barrier needed, same-wave producer/consumer)
#pragma unroll
    for (int ks = 0; ks < 4; ks++)
#pragma unroll
      for (int r = 0; r < 4; r++) {
        const int q = lg * 4 + r, kv = ks * 16 + lr;
        *(unsigned short*)((char*)pw + q * 128 + ((kv * 2) ^ ((q & 7) << 4))) = f2bf(s[ks][r]);
      }

    const char* pr = (const char*)pw + lr * 128;
    bf16x8 pa0 = *reinterpret_cast<const bf16x8*>(pr + ((lg * 16) ^ xsw));
    bf16x8 pa1 = *reinterpret_cast<const bf16x8*>(pr + ((64 + lg * 16) ^ xsw));

    // PV: O += P[16x64] * V[64x64]
#pragma unroll
    for (int dv = 0; dv < 4; dv++) {
      const char* rb = vt + (dv * 16 + lr) * 128;
      bf16x8 vb0 = *reinterpret_cast<const bf16x8*>(rb + ((lg * 16) ^ xsw));
      bf16x8 vb1 = *reinterpret_cast<const bf16x8*>(rb + ((64 + lg * 16) ^ xsw));
      accO[dv] = mfma16(pa0, vb0, accO[dv]);
      accO[dv] = mfma16(pa1, vb1, accO[dv]);
    }
    cur ^= 1;
  }

  // normalize + store (standard [s][1024] layout for the output GEMM)
#pragma unroll
  for (int dv = 0; dv < 4; dv++)
#pragma unroll
    for (int r = 0; r < 4; r++) {
      const int row = q0 + wid * 16 + lg * 4 + r;
      const int col = h * HD + dv * 16 + lr;
      Ob[(size_t)row * DM + col] = f2bf(accO[dv][r] / lrow[r]);
    }
}

// ---------- launch ----------
extern "C" void kernel_launch(void* const* d_in, const int* in_sizes, int n_in,
                              void* d_out, int out_size, void* d_ws, size_t ws_size,
                              hipStream_t stream) {
  const float* queries = (const float*)d_in[0];
  const float* keys    = (const float*)d_in[1];
  const float* values  = (const float*)d_in[2];
  const float* Wq = (const float*)d_in[3];
  const float* bq = (const float*)d_in[4];
  const float* Wk = (const float*)d_in[5];
  const float* bk = (const float*)d_in[6];
  const float* Wv = (const float*)d_in[7];
  const float* bv = (const float*)d_in[8];
  const float* Wo = (const float*)d_in[9];
  const float* bo = (const float*)d_in[10];
  float* out = (float*)d_out;

  const size_t SD = (size_t)SQL * DM;  // 4M elems
  const size_t DD = (size_t)DM * DM;   // 1M elems

  unsigned short* p = (unsigned short*)d_ws;
  unsigned short* xq = p; p += SD;
  unsigned short* xk = p; p += SD;
  unsigned short* xv = p; p += SD;
  unsigned short* wq = p; p += DD;
  unsigned short* wk = p; p += DD;
  unsigned short* wv = p; p += DD;
  unsigned short* wo = p; p += DD;
  unsigned short* Qh = p; p += SD;   // [h][s][64]
  unsigned short* Kh = p; p += SD;   // [h][s][64]
  unsigned short* VTg = p; p += SD;  // [h][64][s]
  unsigned short* Ob = xq;           // alias: xq dead after QKV GEMM

  const int ncvt = (int)((3 * SD + 4 * DD) / 1024);
  cvt_all<<<ncvt, 256, 0, stream>>>(queries, keys, values, Wq, Wk, Wv, Wo, xq);

  gemm_qkv<<<dim3(DM / 128, SQL / 128, 3), 256, 0, stream>>>(
      xq, xk, xv, wq, wk, wv, bq, bk, bv, Qh, Kh, VTg);

  attn_fwd<<<1024, 256, 0, stream>>>(Qh, Kh, VTg, Ob);

  gemm_out<<<dim3(DM / 128, SQL / 128), 256, 0, stream>>>(Ob, wo, bo, out);
}

// Round 5
// 322.486 us; speedup vs baseline: 1.5765x; 1.0291x over previous
//
#include <hip/hip_runtime.h>

#define DEVI __device__ __forceinline__

typedef __attribute__((ext_vector_type(8))) short bf16x8;
typedef __attribute__((ext_vector_type(4))) float f32x4;
typedef __attribute__((ext_vector_type(16))) float f32x16;

#define SQL 4096
#define DM 1024
#define NH 16
#define HD 64
#define S64 (SQL * HD)  // per-head plane elems

// ---------- helpers ----------
DEVI unsigned short f2bf(float f) {
  unsigned int u = __float_as_uint(f);
  unsigned int r = (u + 0x7FFFu + ((u >> 16) & 1u)) >> 16;
  return (unsigned short)r;
}

DEVI void gl16(const void* g, void* l) {
  __builtin_amdgcn_global_load_lds((const __attribute__((address_space(1))) void*)g,
                                   (__attribute__((address_space(3))) void*)l, 16, 0, 0);
}

DEVI f32x4 mfma16(bf16x8 a, bf16x8 b, f32x4 c) {
  return __builtin_amdgcn_mfma_f32_16x16x32_bf16(a, b, c, 0, 0, 0);
}
DEVI f32x16 mfma32(bf16x8 a, bf16x8 b, f32x16 c) {
  return __builtin_amdgcn_mfma_f32_32x32x16_bf16(a, b, c, 0, 0, 0);
}

DEVI unsigned cvtpk(float lo, float hi) {
  unsigned r;
  asm("v_cvt_pk_bf16_f32 %0, %1, %2" : "=v"(r) : "v"(lo), "v"(hi));
  return r;
}

// ---------- fused fp32 -> bf16 convert (7 tensors, 1 dispatch) ----------
__global__ void cvt_all(const float* __restrict__ q, const float* __restrict__ k,
                        const float* __restrict__ v, const float* __restrict__ Wq,
                        const float* __restrict__ Wk, const float* __restrict__ Wv,
                        const float* __restrict__ Wo, unsigned short* __restrict__ o) {
  const size_t SD = (size_t)SQL * DM, DD = (size_t)DM * DM;
  size_t i = ((size_t)blockIdx.x * 256 + threadIdx.x) * 4;
  const float* src;
  size_t base;
  if (i < SD) { src = q; base = 0; }
  else if (i < 2 * SD) { src = k; base = SD; }
  else if (i < 3 * SD) { src = v; base = 2 * SD; }
  else if (i < 3 * SD + DD) { src = Wq; base = 3 * SD; }
  else if (i < 3 * SD + 2 * DD) { src = Wk; base = 3 * SD + DD; }
  else if (i < 3 * SD + 3 * DD) { src = Wv; base = 3 * SD + 2 * DD; }
  else { src = Wo; base = 3 * SD + 3 * DD; }
  float4 vv = *reinterpret_cast<const float4*>(src + (i - base));
  ushort4 ov;
  ov.x = f2bf(vv.x); ov.y = f2bf(vv.y); ov.z = f2bf(vv.z); ov.w = f2bf(vv.w);
  *reinterpret_cast<ushort4*>(o + i) = ov;
}

// ---------- batched QKV GEMM ----------
// C[4096,1024] = A[4096,1024] * B[1024,1024]^T + bias
// z=0 -> Qh [h][s][d] scaled by 0.125*log2(e); z=1 -> Kh [h][s][d];
// z=2 -> VT [h][d][s] via LDS transpose (coalesced stores)
__global__ __launch_bounds__(256) void gemm_qkv(
    const unsigned short* __restrict__ xq, const unsigned short* __restrict__ xk,
    const unsigned short* __restrict__ xv, const unsigned short* __restrict__ wq,
    const unsigned short* __restrict__ wk, const unsigned short* __restrict__ wv,
    const float* __restrict__ bq, const float* __restrict__ bk, const float* __restrict__ bv,
    unsigned short* __restrict__ Qh, unsigned short* __restrict__ Kh,
    unsigned short* __restrict__ VT) {
  __shared__ __align__(16) unsigned short smem[17408];  // lA(8192) + lB(8192); z=2: [128][136]
  unsigned short* lA = smem;
  unsigned short* lB = smem + 8192;
  const int z = blockIdx.z;
  const unsigned short* A = (z == 0) ? xq : (z == 1) ? xk : xv;
  const unsigned short* B = (z == 0) ? wq : (z == 1) ? wk : wv;
  const float* bias = (z == 0) ? bq : (z == 1) ? bk : bv;

  const int t = threadIdx.x;
  const int wid = t >> 6, lane = t & 63, lr = lane & 15, lg = lane >> 4;
  const int wm = wid >> 1, wn = wid & 1;
  const int m0 = blockIdx.y * 128, n0 = blockIdx.x * 128;
  const int K = DM;

  f32x4 acc[4][4] = {};

  for (int kb = 0; kb < K; kb += 64) {
    __syncthreads();
#pragma unroll
    for (int i = 0; i < 4; i++) {
      const int u = i * 256 + t;
      const int row = u >> 3;
      const int ke = (u & 7) * 8;
      unsigned short* la = lA + (size_t)(i * 256 + wid * 64) * 8;
      unsigned short* lb = lB + (size_t)(i * 256 + wid * 64) * 8;
      gl16(A + (size_t)(m0 + row) * K + kb + ke, la);
      gl16(B + (size_t)(n0 + row) * K + kb + ke, lb);
    }
    __syncthreads();
#pragma unroll
    for (int kk = 0; kk < 2; kk++) {
      bf16x8 af[4], bfr[4];
#pragma unroll
      for (int m = 0; m < 4; m++)
        af[m] = *reinterpret_cast<const bf16x8*>(&lA[(wm * 64 + m * 16 + lr) * 64 + kk * 32 + lg * 8]);
#pragma unroll
      for (int n = 0; n < 4; n++)
        bfr[n] = *reinterpret_cast<const bf16x8*>(&lB[(wn * 64 + n * 16 + lr) * 64 + kk * 32 + lg * 8]);
#pragma unroll
      for (int m = 0; m < 4; m++)
#pragma unroll
        for (int n = 0; n < 4; n++)
          acc[m][n] = mfma16(af[m], bfr[n], acc[m][n]);
    }
  }

  if (z < 2) {
    const float sc = (z == 0) ? 0.18033688f : 1.0f;  // 0.125 * log2(e) folded into Q
    unsigned short* dst = (z == 0) ? Qh : Kh;
#pragma unroll
    for (int m = 0; m < 4; m++)
#pragma unroll
      for (int n = 0; n < 4; n++) {
        const int col = n0 + wn * 64 + n * 16 + lr;
        const int hh = col >> 6, d = col & 63;
        const int row0 = m0 + wm * 64 + m * 16 + lg * 4;
        const float bsv = bias[col];
#pragma unroll
        for (int r = 0; r < 4; r++)
          dst[(size_t)hh * S64 + (size_t)(row0 + r) * HD + d] = f2bf((acc[m][n][r] + bsv) * sc);
      }
  } else {
    __syncthreads();
#pragma unroll
    for (int m = 0; m < 4; m++)
#pragma unroll
      for (int n = 0; n < 4; n++) {
        const int col = n0 + wn * 64 + n * 16 + lr;
        const int dt = wn * 64 + n * 16 + lr;  // d within tile
        const float bsv = bias[col];
#pragma unroll
        for (int r = 0; r < 4; r++) {
          const int st = wm * 64 + m * 16 + lg * 4 + r;  // s within tile
          smem[dt * 136 + st] = f2bf(acc[m][n][r] + bsv);
        }
      }
    __syncthreads();
#pragma unroll
    for (int it = 0; it < 8; it++) {
      const int u = it * 256 + t;
      const int d = u >> 4, sc8 = (u & 15) * 8;
      const int col = n0 + d, hh = col >> 6, dd = col & 63;
      *reinterpret_cast<uint4*>(VT + (size_t)hh * S64 + (size_t)dd * SQL + m0 + sc8) =
          *reinterpret_cast<const uint4*>(&smem[d * 136 + sc8]);
    }
  }
}

// ---------- final GEMM: out[M,N] fp32 = A[M,K] * B[N,K]^T + bias ----------
__global__ __launch_bounds__(256) void gemm_out(
    const unsigned short* __restrict__ A, const unsigned short* __restrict__ B,
    const float* __restrict__ bias, float* __restrict__ C) {
  __shared__ __align__(16) unsigned short lA[128 * 64];
  __shared__ __align__(16) unsigned short lB[128 * 64];
  const int t = threadIdx.x;
  const int wid = t >> 6, lane = t & 63, lr = lane & 15, lg = lane >> 4;
  const int wm = wid >> 1, wn = wid & 1;
  const int m0 = blockIdx.y * 128, n0 = blockIdx.x * 128;
  const int K = DM, N = DM;

  f32x4 acc[4][4] = {};

  for (int kb = 0; kb < K; kb += 64) {
    __syncthreads();
#pragma unroll
    for (int i = 0; i < 4; i++) {
      const int u = i * 256 + t;
      const int row = u >> 3;
      const int ke = (u & 7) * 8;
      unsigned short* la = lA + (size_t)(i * 256 + wid * 64) * 8;
      unsigned short* lb = lB + (size_t)(i * 256 + wid * 64) * 8;
      gl16(A + (size_t)(m0 + row) * K + kb + ke, la);
      gl16(B + (size_t)(n0 + row) * K + kb + ke, lb);
    }
    __syncthreads();
#pragma unroll
    for (int kk = 0; kk < 2; kk++) {
      bf16x8 af[4], bfr[4];
#pragma unroll
      for (int m = 0; m < 4; m++)
        af[m] = *reinterpret_cast<const bf16x8*>(&lA[(wm * 64 + m * 16 + lr) * 64 + kk * 32 + lg * 8]);
#pragma unroll
      for (int n = 0; n < 4; n++)
        bfr[n] = *reinterpret_cast<const bf16x8*>(&lB[(wn * 64 + n * 16 + lr) * 64 + kk * 32 + lg * 8]);
#pragma unroll
      for (int m = 0; m < 4; m++)
#pragma unroll
        for (int n = 0; n < 4; n++)
          acc[m][n] = mfma16(af[m], bfr[n], acc[m][n]);
    }
  }

#pragma unroll
  for (int m = 0; m < 4; m++)
#pragma unroll
    for (int n = 0; n < 4; n++)
#pragma unroll
      for (int r = 0; r < 4; r++) {
        const int row = m0 + wm * 64 + m * 16 + lg * 4 + r;
        const int col = n0 + wn * 64 + n * 16 + lr;
        C[(size_t)row * N + col] = acc[m][n][r] + bias[col];
      }
}

// ---------- causal flash attention, swapped-operand 32x32 ----------
// 1024 blocks x 128 threads (2 waves, 32 q-rows each). KV tile 64, dbuf.
// S^T = mfma(K, Q^T): lane owns full score row for q = lane&31.
// O^T = mfma(V^T, P^T): q stays lane-local; al and 1/l are per-lane scalars.
// Q pre-scaled by 0.125*log2(e) -> softmax in exp2 domain.
__global__ __launch_bounds__(128) void attn_fwd(
    const unsigned short* __restrict__ Qh, const unsigned short* __restrict__ Kh,
    const unsigned short* __restrict__ VT, unsigned short* __restrict__ Ob) {
  const int bid = blockIdx.x;
  const int h = bid & 15;
  const int i6 = bid >> 4;
  const int jj = i6 & 15, bb = i6 >> 4;  // window-balanced qt map
  const int qt = (bb & 1) ? (bb * 16 + 15 - jj) : (bb * 16 + jj);
  const int t = threadIdx.x;
  const int wid = t >> 6, lane = t & 63;
  const int ql = lane & 31, hi = lane >> 5;
  const int q0 = qt * 64;
  const int q_g = q0 + wid * 32 + ql;

  __shared__ __align__(16) unsigned short Kt[2][4096];
  __shared__ __align__(16) unsigned short Vt[2][4096];

  const unsigned short* Kp = Kh + (size_t)h * S64;
  const unsigned short* Vp = VT + (size_t)h * S64;

  // Q B-fragments: lane supplies col q=ql, k = 16c + hi*8 + j
  bf16x8 qf[4];
  {
    const unsigned short* qp = Qh + (size_t)h * S64 + (size_t)q_g * HD + hi * 8;
#pragma unroll
    for (int c = 0; c < 4; c++)
      qf[c] = *reinterpret_cast<const bf16x8*>(qp + c * 16);
  }

  f32x16 accO[2] = {};  // O^T: rows d = 32*dc + crow(r,hi), col q = ql
  float m = -INFINITY, l = 0.f;

  const int xm = (ql & 7) << 4;  // read-side XOR swizzle
  const int ntile = qt + 1;

  // prologue: stage tile 0 -> buf 0 (K rows kv, V^T rows d; source pre-swizzled)
#pragma unroll
  for (int ro = 0; ro < 4; ro++) {
    const int u = ro * 128 + t;
    const int row = u >> 3, slot = (u & 7) ^ (row & 7);
    gl16(Kp + (size_t)row * HD + slot * 8, &Kt[0][(ro * 128 + wid * 64) * 8]);
    gl16(Vp + (size_t)row * SQL + slot * 8, &Vt[0][(ro * 128 + wid * 64) * 8]);
  }

  int cur = 0;
  for (int tk = 0; tk < ntile; tk++) {
    const int kv0 = tk * 64;
    __syncthreads();  // buf[cur] landed for all waves

    if (tk + 1 < ntile) {
      const int nkv = kv0 + 64;
      unsigned short* kdb = Kt[cur ^ 1];
      unsigned short* vdb = Vt[cur ^ 1];
#pragma unroll
      for (int ro = 0; ro < 4; ro++) {
        const int u = ro * 128 + t;
        const int row = u >> 3, slot = (u & 7) ^ (row & 7);
        gl16(Kp + (size_t)(nkv + row) * HD + slot * 8, kdb + (ro * 128 + wid * 64) * 8);
        gl16(Vp + (size_t)row * SQL + nkv + slot * 8, vdb + (ro * 128 + wid * 64) * 8);
      }
    }

    const char* kt = (const char*)Kt[cur];
    const char* vt = (const char*)Vt[cur];

    // QK^T swapped: sA[kc][r] = S^T[kv = 32kc+crow(r,hi)][q = ql]
    f32x16 sA[2];
    __builtin_amdgcn_s_setprio(1);
#pragma unroll
    for (int kc = 0; kc < 2; kc++) {
      const char* rb = kt + (32 * kc + ql) * 128;
      f32x16 a = {};
#pragma unroll
      for (int c = 0; c < 4; c++) {
        bf16x8 kf = *reinterpret_cast<const bf16x8*>(rb + ((c * 32 + hi * 16) ^ xm));
        a = mfma32(kf, qf[c], a);
      }
      sA[kc] = a;
    }
    __builtin_amdgcn_s_setprio(0);

    // causal mask (diagonal tile only)
    if (tk == qt) {
#pragma unroll
      for (int kc = 0; kc < 2; kc++)
#pragma unroll
        for (int r = 0; r < 16; r++) {
          const int kv_g = kv0 + 32 * kc + (r & 3) + 8 * (r >> 2) + 4 * hi;
          if (kv_g > q_g) sA[kc][r] = -INFINITY;
        }
    }

    // online softmax (exp2 domain), defer-max THR=8
    float pm = sA[0][0];
#pragma unroll
    for (int r = 1; r < 16; r++) pm = fmaxf(pm, sA[0][r]);
#pragma unroll
    for (int r = 0; r < 16; r++) pm = fmaxf(pm, sA[1][r]);
    pm = fmaxf(pm, __shfl_xor(pm, 32));
    if (!__all(pm - m <= 8.f)) {
      const float mn = fmaxf(m, pm);
      const float al = exp2f(m - mn);
      m = mn;
      l *= al;
#pragma unroll
      for (int dc = 0; dc < 2; dc++)
#pragma unroll
        for (int r = 0; r < 16; r++) accO[dc][r] *= al;
    }
    float sum = 0.f;
#pragma unroll
    for (int kc = 0; kc < 2; kc++)
#pragma unroll
      for (int r = 0; r < 16; r++) {
        const float e = exp2f(sA[kc][r] - m);
        sA[kc][r] = e;
        sum += e;
      }
    sum += __shfl_xor(sum, 32);
    l += sum;

    // P -> PV B-fragments: lane needs kv = 16ck + 8hi + j; own regs hold
    // kv = {0..3,8..11}+4hi per 16-block -> pack pairs, exchange across lane^32
    bf16x8 pf[4];
#pragma unroll
    for (int ck = 0; ck < 4; ck++) {
      const int kc = ck >> 1, rb0 = (ck & 1) * 8;
      unsigned lo0 = cvtpk(sA[kc][rb0 + 0], sA[kc][rb0 + 1]);
      unsigned lo1 = cvtpk(sA[kc][rb0 + 2], sA[kc][rb0 + 3]);
      unsigned h0  = cvtpk(sA[kc][rb0 + 4], sA[kc][rb0 + 5]);
      unsigned h1  = cvtpk(sA[kc][rb0 + 6], sA[kc][rb0 + 7]);
      unsigned xl0 = (unsigned)__shfl_xor((int)lo0, 32);
      unsigned xl1 = (unsigned)__shfl_xor((int)lo1, 32);
      unsigned xh0 = (unsigned)__shfl_xor((int)h0, 32);
      unsigned xh1 = (unsigned)__shfl_xor((int)h1, 32);
      unsigned* pw = (unsigned*)&pf[ck];
      pw[0] = hi ? xh0 : lo0;
      pw[1] = hi ? xh1 : lo1;
      pw[2] = hi ? h0 : xl0;
      pw[3] = hi ? h1 : xl1;
    }

    // PV swapped: accO[dc] += V^T[32dc+crow][kv] * P^T[kv][q]
    __builtin_amdgcn_s_setprio(1);
#pragma unroll
    for (int dc = 0; dc < 2; dc++) {
      const char* rb = vt + (32 * dc + ql) * 128;
#pragma unroll
      for (int ck = 0; ck < 4; ck++) {
        bf16x8 vf = *reinterpret_cast<const bf16x8*>(rb + ((ck * 32 + hi * 16) ^ xm));
        accO[dc] = mfma32(vf, pf[ck], accO[dc]);
      }
    }
    __builtin_amdgcn_s_setprio(0);
    cur ^= 1;
  }

  // normalize + store: lane holds 32 d-values for its single q row
  const float inv = 1.f / l;
  unsigned short* ob = Ob + (size_t)q_g * DM + h * HD;
#pragma unroll
  for (int dc = 0; dc < 2; dc++)
#pragma unroll
    for (int tq = 0; tq < 4; tq++) {
      ushort4 o;
      o.x = f2bf(accO[dc][tq * 4 + 0] * inv);
      o.y = f2bf(accO[dc][tq * 4 + 1] * inv);
      o.z = f2bf(accO[dc][tq * 4 + 2] * inv);
      o.w = f2bf(accO[dc][tq * 4 + 3] * inv);
      *reinterpret_cast<ushort4*>(ob + dc * 32 + tq * 8 + hi * 4) = o;
    }
}

// ---------- launch ----------
extern "C" void kernel_launch(void* const* d_in, const int* in_sizes, int n_in,
                              void* d_out, int out_size, void* d_ws, size_t ws_size,
                              hipStream_t stream) {
  const float* queries = (const float*)d_in[0];
  const float* keys    = (const float*)d_in[1];
  const float* values  = (const float*)d_in[2];
  const float* Wq = (const float*)d_in[3];
  const float* bq = (const float*)d_in[4];
  const float* Wk = (const float*)d_in[5];
  const float* bk = (const float*)d_in[6];
  const float* Wv = (const float*)d_in[7];
  const float* bv = (const float*)d_in[8];
  const float* Wo = (const float*)d_in[9];
  const float* bo = (const float*)d_in[10];
  float* out = (float*)d_out;

  const size_t SD = (size_t)SQL * DM;
  const size_t DD = (size_t)DM * DM;

  unsigned short* p = (unsigned short*)d_ws;
  unsigned short* xq = p; p += SD;
  unsigned short* xk = p; p += SD;
  unsigned short* xv = p; p += SD;
  unsigned short* wq = p; p += DD;
  unsigned short* wk = p; p += DD;
  unsigned short* wv = p; p += DD;
  unsigned short* wo = p; p += DD;
  unsigned short* Qh = p; p += SD;   // [h][s][64], pre-scaled
  unsigned short* Kh = p; p += SD;   // [h][s][64]
  unsigned short* VTg = p; p += SD;  // [h][64][s]
  unsigned short* Ob = xq;           // alias: xq dead after QKV GEMM

  const int ncvt = (int)((3 * SD + 4 * DD) / 1024);
  cvt_all<<<ncvt, 256, 0, stream>>>(queries, keys, values, Wq, Wk, Wv, Wo, xq);

  gemm_qkv<<<dim3(DM / 128, SQL / 128, 3), 256, 0, stream>>>(
      xq, xk, xv, wq, wk, wv, bq, bk, bv, Qh, Kh, VTg);

  attn_fwd<<<1024, 128, 0, stream>>>(Qh, Kh, VTg, Ob);

  gemm_out<<<dim3(DM / 128, SQL / 128), 256, 0, stream>>>(Ob, wo, bo, out);
}